// Round 10
// baseline (417.211 us; speedup 1.0000x reference)
//
#include <hip/hip_runtime.h>
#include <hip/hip_bf16.h>

using uint32 = unsigned int;
using u16 = unsigned short;
using short8 = __attribute__((ext_vector_type(8))) short;
using f32x4  = __attribute__((ext_vector_type(4))) float;
using f32x16 = __attribute__((ext_vector_type(16))) float;

// ---------- bf16 helpers ----------
__device__ __forceinline__ float bf2f(u16 u) {
  union { uint32 i; float f; } c; c.i = ((uint32)u) << 16; return c.f;
}
__device__ __forceinline__ u16 f2bf(float f) {
  union { float f; uint32 i; } c; c.f = f;
  uint32 u = c.i;
  u += 0x7fffu + ((u >> 16) & 1u);   // RNE
  return (u16)(u >> 16);
}
__device__ __forceinline__ uint32 pack2(float a, float b) {
  return (uint32)f2bf(a) | ((uint32)f2bf(b) << 16);
}

// async global->LDS, 16B per lane. LDS dest: wave-uniform base (+lane*16 by HW);
// global src: per-lane address.
__device__ __forceinline__ void gload_lds16(const void* g, void* l) {
  __builtin_amdgcn_global_load_lds(
      (const __attribute__((address_space(1))) unsigned int*)g,
      (__attribute__((address_space(3))) unsigned int*)l, 16, 0, 0);
}

// Sizes: B=16, C=64, W=256, H=128, H'=122, KW=7
// k/q layout: [b][co][w][h'] contiguous == (B,256,7808) attention rows
// raw flatten: row j=(c=j>>2, wblk=j&3); col e=(dw=e>>7, h=e&127)
// x/z tiles: per (b,w) [128 h][64 ci^((h&7)<<3)] bf16, 16384B

// ---------------------------------------------------------------
// Kernel 0: prep weights -> bf16 [kw][co][ci]
// ---------------------------------------------------------------
__global__ __launch_bounds__(256) void prep_weights(
    const float* __restrict__ wK, const float* __restrict__ wQ,
    const float* __restrict__ wV,
    u16* __restrict__ pK, u16* __restrict__ pQ, u16* __restrict__ pV)
{
  int idx = blockIdx.x * 256 + threadIdx.x;   // 0..86015
  if (idx >= 86016) return;
  int set = idx / 28672;
  int r = idx - set * 28672;                  // kw*4096 + co*64 + ci
  int kw = r >> 12;
  int rem = r & 4095;
  int co = rem >> 6, ci = rem & 63;
  const float* src = set == 0 ? wK : (set == 1 ? wQ : wV);
  u16* dst = set == 0 ? pK : (set == 1 ? pQ : pV);
  dst[r] = f2bf(src[co * 448 + ci * 7 + kw]);
}

// ---------------------------------------------------------------
// Kernel 0b: x -> swizzled bf16 tiles (streaming, full occupancy)
// ---------------------------------------------------------------
__global__ __launch_bounds__(256) void prep_x(
    const float* __restrict__ x, u16* __restrict__ xbuf)
{
  __shared__ u16 xt[128 * 64];
  const int bid = blockIdx.x;         // b*256 + w
  const int b = bid >> 8, w = bid & 255;
  const int t = threadIdx.x;
  const float* xb = x + (size_t)b * 2097152 + (size_t)w * 128;
  #pragma unroll
  for (int it = 0; it < 8; ++it) {
    int idx = t + it * 256;
    int h = idx & 127, gq = idx >> 7;
    int ci0 = gq * 4;
    float v0 = xb[(size_t)(ci0 + 0) * 32768 + h];
    float v1 = xb[(size_t)(ci0 + 1) * 32768 + h];
    float v2 = xb[(size_t)(ci0 + 2) * 32768 + h];
    float v3 = xb[(size_t)(ci0 + 3) * 32768 + h];
    uint2 pk; pk.x = pack2(v0, v1); pk.y = pack2(v2, v3);
    int col = ci0 ^ ((h & 7) << 3);
    *reinterpret_cast<uint2*>(&xt[h * 64 + col]) = pk;
  }
  __syncthreads();
  const uint4* s = reinterpret_cast<const uint4*>(xt);
  uint4* d = reinterpret_cast<uint4*>(xbuf + (size_t)bid * 8192);
  #pragma unroll
  for (int it = 0; it < 4; ++it) d[t + it * 256] = s[t + it * 256];
}

// ---------------------------------------------------------------
// Kernel 1: K and Q convs via 32x32x16 MFMA. Staging = global_load_lds
// of the pre-swizzled tile. Wave = (mi co-half, nh n-half); B-frag shared
// across K/Q and both jn. Epilogue: LDS transpose -> coalesced u32 rows.
// A/B frag: row(col)=lane&31, k=(lane>>5)*8+[0..8).
// C/D frag: col=lane&31, row=(r&3)+8*(r>>2)+4*(lane>>5).
// ---------------------------------------------------------------
__global__ __launch_bounds__(256, 3) void conv_kq_mfma(
    const u16* __restrict__ xbuf,
    const u16* __restrict__ wpK, const u16* __restrict__ wpQ,
    const float* __restrict__ bK, const float* __restrict__ bQ,
    u16* __restrict__ qbuf, u16* __restrict__ kbuf)
{
  __shared__ u16 xt[136 * 64];   // staging tile; reused as zs[64 co][136 n]
  const int bid = blockIdx.x;
  const int b = bid >> 8, w = bid & 255;
  const int t = threadIdx.x;
  const int lane = t & 63, wv = t >> 6;
  const int l31 = lane & 31, kg = lane >> 5;
  const int mi = wv >> 1, nh = wv & 1;

  {
    const u16* src = xbuf + (size_t)bid * 8192;
    #pragma unroll
    for (int c = 0; c < 4; ++c) {
      int chunk = wv * 4 + c;                       // 16 chunks x 1024B
      gload_lds16(src + chunk * 512 + lane * 8, &xt[chunk * 512]);
    }
    if (t < 128) {   // zero pad rows 128..135
      *reinterpret_cast<uint2*>(&xt[128 * 64 + t * 4]) = make_uint2(0u, 0u);
    }
  }
  asm volatile("s_waitcnt vmcnt(0)" ::: "memory");
  __syncthreads();

  f32x16 accK[2], accQ[2];
  accK[0] = (f32x16)0.f; accK[1] = (f32x16)0.f;
  accQ[0] = (f32x16)0.f; accQ[1] = (f32x16)0.f;

  for (int kw = 0; kw < 7; ++kw) {
    #pragma unroll
    for (int ks = 0; ks < 4; ++ks) {
      const int kb = ks * 16 + kg * 8;
      const size_t woff = (size_t)(kw * 64 + mi * 32 + l31) * 64 + kb;
      short8 aK = *reinterpret_cast<const short8*>(wpK + woff);
      short8 aQ = *reinterpret_cast<const short8*>(wpQ + woff);
      #pragma unroll
      for (int jn = 0; jn < 2; ++jn) {
        int row = (nh * 2 + jn) * 32 + l31 + kw;
        int col = kb ^ ((row & 7) << 3);
        short8 bf = *reinterpret_cast<const short8*>(&xt[row * 64 + col]);
        accK[jn] = __builtin_amdgcn_mfma_f32_32x32x16_bf16(aK, bf, accK[jn], 0, 0, 0);
        accQ[jn] = __builtin_amdgcn_mfma_f32_32x32x16_bf16(aQ, bf, accQ[jn], 0, 0, 0);
      }
    }
  }
  __syncthreads();   // xt dead -> reuse as zs

  u16* zs = xt;      // [64 co][136 n] u16
  #pragma unroll
  for (int p = 0; p < 2; ++p) {
    #pragma unroll
    for (int jn = 0; jn < 2; ++jn) {
      int n = (nh * 2 + jn) * 32 + l31;
      if (n < 122) {
        #pragma unroll
        for (int r = 0; r < 16; ++r) {
          int co = mi * 32 + (r & 3) + 8 * (r >> 2) + 4 * kg;
          float bias = p ? bQ[co] : bK[co];
          float v = p ? accQ[jn][r] : accK[jn][r];
          zs[co * 136 + n] = f2bf(v + bias);
        }
      }
    }
    __syncthreads();
    // copy-out: 64 rows x 61 u32 (244B contiguous per (co,w) row)
    const uint32* zw = reinterpret_cast<const uint32*>(zs);
    uint32* dst = reinterpret_cast<uint32*>(p ? qbuf : kbuf);
    #pragma unroll
    for (int pass = 0; pass < 16; ++pass) {
      int idx = t + pass * 256;        // 0..4095
      int co = idx >> 6, u = idx & 63;
      if (u < 61)
        dst[((size_t)(b * 64 + co) * 256 + w) * 61 + u] = zw[co * 68 + u];
    }
    __syncthreads();
  }
}

// ---------------------------------------------------------------
// Kernel 2a: scores via MFMA + fused masked softmax -> pbuf bf16
// ---------------------------------------------------------------
__global__ __launch_bounds__(256) void scores_mfma(
    const u16* __restrict__ qbuf, const u16* __restrict__ kbuf,
    u16* __restrict__ pbuf)
{
  __shared__ float lmax[4][16];
  __shared__ float lsum[4][16];
  const int bid = blockIdx.x;
  const int b = bid & 15, rt = bid >> 4;
  const int t = threadIdx.x;
  const int lane = t & 63, wq = t >> 6;
  const int g = lane >> 4, ln = lane & 15;
  const int i0 = rt * 16;
  const int jbase = (rt < 8) ? 128 : 0;

  const u16* qp  = qbuf + (size_t)(b * 256 + i0 + ln) * 7808 + g * 8;
  const u16* kp0 = kbuf + (size_t)(b * 256 + jbase + wq * 32 + ln) * 7808 + g * 8;
  const u16* kp1 = kp0 + (size_t)16 * 7808;

  f32x4 acc0 = (f32x4)0.f, acc1 = (f32x4)0.f;
  #pragma unroll 4
  for (int c = 0; c < 244; ++c) {
    short8 af = *reinterpret_cast<const short8*>(qp + c * 32);
    short8 b0 = *reinterpret_cast<const short8*>(kp0 + c * 32);
    short8 b1 = *reinterpret_cast<const short8*>(kp1 + c * 32);
    acc0 = __builtin_amdgcn_mfma_f32_16x16x32_bf16(af, b0, acc0, 0, 0, 0);
    acc1 = __builtin_amdgcn_mfma_f32_16x16x32_bf16(af, b1, acc1, 0, 0, 0);
  }

  const float scale = 0.011316967f;    // 1/sqrt(7808)
  float s0[4], s1[4];
  #pragma unroll
  for (int r = 0; r < 4; ++r) { s0[r] = acc0[r] * scale; s1[r] = acc1[r] * scale; }

  float pm[4], ps[4];
  #pragma unroll
  for (int r = 0; r < 4; ++r) {
    float m = fmaxf(s0[r], s1[r]);
    #pragma unroll
    for (int off = 8; off >= 1; off >>= 1) m = fmaxf(m, __shfl_xor(m, off));
    float e = __expf(s0[r] - m) + __expf(s1[r] - m);
    #pragma unroll
    for (int off = 8; off >= 1; off >>= 1) e += __shfl_xor(e, off);
    pm[r] = m; ps[r] = e;
  }
  if (ln == 0) {
    #pragma unroll
    for (int r = 0; r < 4; ++r) {
      lmax[wq][g * 4 + r] = pm[r];
      lsum[wq][g * 4 + r] = ps[r];
    }
  }
  __syncthreads();

  #pragma unroll
  for (int r = 0; r < 4; ++r) {
    int row = g * 4 + r;
    float m0 = lmax[0][row], m1 = lmax[1][row], m2 = lmax[2][row], m3 = lmax[3][row];
    float mm = fmaxf(fmaxf(m0, m1), fmaxf(m2, m3));
    float ss = lsum[0][row] * __expf(m0 - mm) + lsum[1][row] * __expf(m1 - mm)
             + lsum[2][row] * __expf(m2 - mm) + lsum[3][row] * __expf(m3 - mm);
    float inv = 1.0f / ss;
    float p0 = __expf(s0[r] - mm) * inv;
    float p1 = __expf(s1[r] - mm) * inv;
    u16* prow = pbuf + (size_t)(b * 256 + i0 + row) * 128 + wq * 32 + ln;
    prow[0]  = f2bf(p0);
    prow[16] = f2bf(p1);
  }
}

// ---------------------------------------------------------------
// Kernel 2b: z = x + P*V via MFMA -> swizzled z TILES directly.
// acc[mt][nt][r]: tile w_img = r*64 + ec*2 + (nt>>3), h = (nt&7)*16+ln,
// chan c' = wv*8+mt*4+g (+cbase). Per-tile LDS transpose zs[h][c'] (stride
// 40 -> aligned uint4), copy-out applies the tile XOR swizzle.
// ---------------------------------------------------------------
__global__ __launch_bounds__(256) void pv_mfma(
    const u16* __restrict__ pbuf, const float* __restrict__ x,
    u16* __restrict__ ztbuf)
{
  __shared__ u16 smem[27648];          // pl[128*136] + vt[256*40]; zs overlays
  u16* pl = smem;
  u16* vt = smem + 17408;
  const int bid = blockIdx.x;
  const int b  = bid >> 6;
  const int hb = (bid >> 5) & 1;
  const int ec = bid & 31;
  const int t = threadIdx.x;
  const int lane = t & 63, wv = t >> 6;
  const int ln = lane & 15, g = lane >> 4;

  const int i0 = hb ? 0 : 128;        // output rows
  const int jbase = hb ? 128 : 0;     // V rows (opposite half)
  const int e0 = ec * 256;
  const float* xb = x + (size_t)b * 2097152;

  // stage P (bf16 rows, pad stride 136)
  {
    const u16* pb = pbuf + (size_t)(b * 256 + i0) * 128;
    #pragma unroll
    for (int it = 0; it < 8; ++it) {
      int idx = t + it * 256;           // 0..2047 uint4
      int row = idx >> 4, c = idx & 15;
      uint4 v = *reinterpret_cast<const uint4*>(pb + row * 128 + c * 8);
      *reinterpret_cast<uint4*>(&pl[row * 136 + c * 8]) = v;
    }
  }

  f32x4 acc[2][16];
  #pragma unroll
  for (int mt = 0; mt < 2; ++mt)
    #pragma unroll
    for (int nt = 0; nt < 16; ++nt) acc[mt][nt] = (f32x4)0.f;

  uint32* vtw = reinterpret_cast<uint32*>(vt);
  for (int ks = 0; ks < 4; ++ks) {
    __syncthreads();
    // stage V^T k-step: raw V rows jbase+ks*32..+32, cols e0..e0+256
    #pragma unroll
    for (int it = 0; it < 16; ++it) {
      int idx = t + it * 256;           // 0..4095
      int e = idx & 255, jp = idx >> 8;
      const float* vr = xb + (size_t)(jbase + ks * 32 + jp * 2) * 8192 + e0 + e;
      float f0 = vr[0];
      float f1 = vr[8192];
      vtw[e * 20 + jp] = pack2(f0, f1);
    }
    __syncthreads();
    short8 af[2];
    #pragma unroll
    for (int mt = 0; mt < 2; ++mt) {
      int row = wv * 32 + mt * 16 + ln;
      af[mt] = *reinterpret_cast<const short8*>(&pl[row * 136 + ks * 32 + g * 8]);
    }
    #pragma unroll
    for (int nt = 0; nt < 16; ++nt) {
      int e = nt * 16 + ln;
      short8 bf = *reinterpret_cast<const short8*>(&vt[e * 40 + g * 8]);
      acc[0][nt] = __builtin_amdgcn_mfma_f32_16x16x32_bf16(af[0], bf, acc[0][nt], 0, 0, 0);
      acc[1][nt] = __builtin_amdgcn_mfma_f32_16x16x32_bf16(af[1], bf, acc[1][nt], 0, 0, 0);
    }
  }

  // epilogue: per-tile transpose + swizzled copy-out
  u16* zs = smem;                      // [128 h][40] u16 (stride 40 -> 16B mult)
  const int cb5 = hb ? 0 : 1;          // cbase>>5
  const int cp_base = wv * 8 + g;
  for (int r = 0; r < 4; ++r) {
    for (int dwh = 0; dwh < 2; ++dwh) {
      __syncthreads();
      #pragma unroll
      for (int mt = 0; mt < 2; ++mt) {
        int i = i0 + wv * 32 + mt * 16 + g * 4 + r;
        int cp = cp_base + mt * 4;
        const float* xr = xb + (size_t)i * 8192 + e0 + dwh * 128 + ln;
        #pragma unroll
        for (int q = 0; q < 8; ++q) {
          float z = xr[q * 16] + acc[mt][dwh * 8 + q][r];
          zs[(q * 16 + ln) * 40 + cp] = f2bf(z);
        }
      }
      __syncthreads();
      int wimg = r * 64 + ec * 2 + dwh;
      u16* tb = ztbuf + (size_t)(b * 256 + wimg) * 8192;
      #pragma unroll
      for (int pass = 0; pass < 2; ++pass) {
        int idx = t + pass * 256;      // 0..511
        int h = idx >> 2, ch = idx & 3;
        uint4 v = *reinterpret_cast<const uint4*>(&zs[h * 40 + ch * 8]);
        int blk = 32 * (cb5 ^ ((h >> 2) & 1));
        int chd = ch ^ (h & 3);
        *reinterpret_cast<uint4*>(&tb[h * 64 + blk + chd * 8]) = v;
      }
    }
  }
}

// ---------------------------------------------------------------
// Kernel 3: y = LeakyReLU(conv(z, wV) + bV) via 32x32x16 MFMA, fp32 out.
// Staging via global_load_lds from z tiles; epilogue LDS transpose
// -> coalesced uint2 row stores (488B rows, 8B-aligned).
// ---------------------------------------------------------------
__global__ __launch_bounds__(256, 4) void conv_out_mfma(
    const u16* __restrict__ ztbuf, const u16* __restrict__ wpV,
    const float* __restrict__ bV, float* __restrict__ out)
{
  __shared__ uint32 smem4[8448];       // 33792B: xt (17408) then zs_f32 (33792)
  u16* xt = reinterpret_cast<u16*>(smem4);
  const int bid = blockIdx.x;
  const int b = bid >> 8, w = bid & 255;
  const int t = threadIdx.x;
  const int lane = t & 63, wv = t >> 6;
  const int l31 = lane & 31, kg = lane >> 5;
  const int mi = wv >> 1, nh = wv & 1;

  {
    const u16* src = ztbuf + (size_t)bid * 8192;
    #pragma unroll
    for (int c = 0; c < 4; ++c) {
      int chunk = wv * 4 + c;
      gload_lds16(src + chunk * 512 + lane * 8, &xt[chunk * 512]);
    }
    if (t < 128) {
      *reinterpret_cast<uint2*>(&xt[128 * 64 + t * 4]) = make_uint2(0u, 0u);
    }
  }
  asm volatile("s_waitcnt vmcnt(0)" ::: "memory");
  __syncthreads();

  f32x16 acc[2];
  acc[0] = (f32x16)0.f; acc[1] = (f32x16)0.f;

  for (int kw = 0; kw < 7; ++kw) {
    #pragma unroll
    for (int ks = 0; ks < 4; ++ks) {
      const int kb = ks * 16 + kg * 8;
      const size_t woff = (size_t)(kw * 64 + mi * 32 + l31) * 64 + kb;
      short8 aV = *reinterpret_cast<const short8*>(wpV + woff);
      #pragma unroll
      for (int jn = 0; jn < 2; ++jn) {
        int row = (nh * 2 + jn) * 32 + l31 + kw;
        int col = kb ^ ((row & 7) << 3);
        short8 bf = *reinterpret_cast<const short8*>(&xt[row * 64 + col]);
        acc[jn] = __builtin_amdgcn_mfma_f32_32x32x16_bf16(aV, bf, acc[jn], 0, 0, 0);
      }
    }
  }
  __syncthreads();   // xt dead -> zs

  float* zsf = reinterpret_cast<float*>(smem4);   // [64 co][132 n] f32
  #pragma unroll
  for (int jn = 0; jn < 2; ++jn) {
    int n = (nh * 2 + jn) * 32 + l31;
    if (n < 122) {
      #pragma unroll
      for (int r = 0; r < 16; ++r) {
        int co = mi * 32 + (r & 3) + 8 * (r >> 2) + 4 * kg;
        float y = acc[jn][r] + bV[co];
        zsf[co * 132 + n] = (y >= 0.f) ? y : 0.2f * y;
      }
    }
  }
  __syncthreads();
  // copy-out: 64 rows x 61 uint2 (488B contiguous per (co,w) row)
  const uint2* zw = reinterpret_cast<const uint2*>(zsf);
  #pragma unroll
  for (int pass = 0; pass < 16; ++pass) {
    int idx = t + pass * 256;          // 0..4095
    int co = idx >> 6, u = idx & 63;
    if (u < 61) {
      uint2* dst = reinterpret_cast<uint2*>(
          out + ((size_t)(b * 64 + co) * 256 + w) * 122);
      dst[u] = zw[co * 66 + u];
    }
  }
}

// ---------------------------------------------------------------
extern "C" void kernel_launch(void* const* d_in, const int* in_sizes, int n_in,
                              void* d_out, int out_size, void* d_ws, size_t ws_size,
                              hipStream_t stream) {
  const float* x  = (const float*)d_in[0];
  const float* wK = (const float*)d_in[1];
  const float* bK = (const float*)d_in[2];
  const float* wQ = (const float*)d_in[3];
  const float* bQ = (const float*)d_in[4];
  const float* wV = (const float*)d_in[5];
  const float* bV = (const float*)d_in[6];
  float* out = (float*)d_out;

  // workspace layout (196,255,744 B total):
  // [0)            qbuf bf16        63,963,136   dead after scores
  // [63,963,136)   kbuf bf16        63,963,136   dead after scores
  // [127,926,272)  pbuf bf16         1,048,576   live scores->pv
  // [128,974,848)  wpK/wpQ/wpV          172,032  (wpV live to conv_out)
  // [129,146,880)  xbuf -> ztbuf    67,108,864   (xbuf dead after conv_kq;
  //                                              pv writes ztbuf there)
  char* ws = (char*)d_ws;
  u16* qbuf  = (u16*)ws;
  u16* kbuf  = (u16*)(ws + 63963136);
  u16* pbuf  = (u16*)(ws + 127926272);
  u16* wpK   = (u16*)(ws + 128974848);
  u16* wpQ   = (u16*)(ws + 129032192);
  u16* wpV   = (u16*)(ws + 129089536);
  u16* xbuf  = (u16*)(ws + 129146880);
  u16* ztbuf = xbuf;

  prep_weights<<<dim3(336), dim3(256), 0, stream>>>(wK, wQ, wV, wpK, wpQ, wpV);
  prep_x<<<dim3(16 * 256), dim3(256), 0, stream>>>(x, xbuf);
  conv_kq_mfma<<<dim3(16 * 256), dim3(256), 0, stream>>>(xbuf, wpK, wpQ, bK, bQ, qbuf, kbuf);
  scores_mfma<<<dim3(256), dim3(256), 0, stream>>>(qbuf, kbuf, pbuf);
  pv_mfma<<<dim3(1024), dim3(256), 0, stream>>>(pbuf, x, ztbuf);
  conv_out_mfma<<<dim3(16 * 256), dim3(256), 0, stream>>>(ztbuf, wpV, bV, out);
}

// Round 11
// 347.823 us; speedup vs baseline: 1.1995x; 1.1995x over previous
//
#include <hip/hip_runtime.h>
#include <hip/hip_bf16.h>

using uint32 = unsigned int;
using u16 = unsigned short;
using short8 = __attribute__((ext_vector_type(8))) short;
using f32x4  = __attribute__((ext_vector_type(4))) float;

// ---------- bf16 helpers ----------
__device__ __forceinline__ float bf2f(u16 u) {
  union { uint32 i; float f; } c; c.i = ((uint32)u) << 16; return c.f;
}
__device__ __forceinline__ u16 f2bf(float f) {
  union { float f; uint32 i; } c; c.f = f;
  uint32 u = c.i;
  u += 0x7fffu + ((u >> 16) & 1u);   // RNE
  return (u16)(u >> 16);
}
__device__ __forceinline__ uint32 pack2(float a, float b) {
  return (uint32)f2bf(a) | ((uint32)f2bf(b) << 16);
}

// async global->LDS, 16B per lane. LDS dest: wave-uniform base (+lane*16 by HW);
// global src: per-lane address.
__device__ __forceinline__ void gload_lds16(const void* g, void* l) {
  __builtin_amdgcn_global_load_lds(
      (const __attribute__((address_space(1))) unsigned int*)g,
      (__attribute__((address_space(3))) unsigned int*)l, 16, 0, 0);
}

// Sizes: B=16, C=64, W=256, H=128, H'=122, KW=7
// q/k stored PADDED: [b][co][w][128] bf16 (cols 122..127 = 0 in both q,k ->
// QK dot over 8192 == dot over 7808 exactly). Row map i=4co+(w>>6) unchanged.
// raw flatten: row j=(c=j>>2, wblk=j&3); col e=(dw=e>>7, h=e&127)
// x/z tiles: per (b,w) [128 h][64 ci^((h&7)<<3)] bf16, 16384B

// ---------------------------------------------------------------
// Kernel 0: prep weights -> bf16 [kw][co][ci]
// ---------------------------------------------------------------
__global__ __launch_bounds__(256) void prep_weights(
    const float* __restrict__ wK, const float* __restrict__ wQ,
    const float* __restrict__ wV,
    u16* __restrict__ pK, u16* __restrict__ pQ, u16* __restrict__ pV)
{
  int idx = blockIdx.x * 256 + threadIdx.x;   // 0..86015
  if (idx >= 86016) return;
  int set = idx / 28672;
  int r = idx - set * 28672;                  // kw*4096 + co*64 + ci
  int kw = r >> 12;
  int rem = r & 4095;
  int co = rem >> 6, ci = rem & 63;
  const float* src = set == 0 ? wK : (set == 1 ? wQ : wV);
  u16* dst = set == 0 ? pK : (set == 1 ? pQ : pV);
  dst[r] = f2bf(src[co * 448 + ci * 7 + kw]);
}

// ---------------------------------------------------------------
// Kernel 0b: x -> swizzled bf16 tiles (streaming, full occupancy)
// ---------------------------------------------------------------
__global__ __launch_bounds__(256) void prep_x(
    const float* __restrict__ x, u16* __restrict__ xbuf)
{
  __shared__ u16 xt[128 * 64];
  const int bid = blockIdx.x;         // b*256 + w
  const int b = bid >> 8, w = bid & 255;
  const int t = threadIdx.x;
  const float* xb = x + (size_t)b * 2097152 + (size_t)w * 128;
  #pragma unroll
  for (int it = 0; it < 8; ++it) {
    int idx = t + it * 256;
    int h = idx & 127, gq = idx >> 7;
    int ci0 = gq * 4;
    float v0 = xb[(size_t)(ci0 + 0) * 32768 + h];
    float v1 = xb[(size_t)(ci0 + 1) * 32768 + h];
    float v2 = xb[(size_t)(ci0 + 2) * 32768 + h];
    float v3 = xb[(size_t)(ci0 + 3) * 32768 + h];
    uint2 pk; pk.x = pack2(v0, v1); pk.y = pack2(v2, v3);
    int col = ci0 ^ ((h & 7) << 3);
    *reinterpret_cast<uint2*>(&xt[h * 64 + col]) = pk;
  }
  __syncthreads();
  const uint4* s = reinterpret_cast<const uint4*>(xt);
  uint4* d = reinterpret_cast<uint4*>(xbuf + (size_t)bid * 8192);
  #pragma unroll
  for (int it = 0; it < 4; ++it) d[t + it * 256] = s[t + it * 256];
}

// ---------------------------------------------------------------
// Kernel 1: K and Q convs via 16x16x32 MFMA (R9-proven K-loop).
// Staging = global_load_lds of pre-swizzled tile. Epilogue: LDS
// transpose -> PADDED rows (256B), fully-coalesced uint4 copy-out.
// ---------------------------------------------------------------
__global__ __launch_bounds__(256, 4) void conv_kq_mfma(
    const u16* __restrict__ xbuf,
    const u16* __restrict__ wpK, const u16* __restrict__ wpQ,
    const float* __restrict__ bK, const float* __restrict__ bQ,
    u16* __restrict__ qbuf, u16* __restrict__ kbuf)
{
  __shared__ u16 xt[136 * 64];   // staging tile; reused as zs[64 co][136 n]
  const int bid = blockIdx.x;
  const int b = bid >> 8, w = bid & 255;
  const int t = threadIdx.x;
  const int lane = t & 63, wv = t >> 6;
  const int ln = lane & 15, g = lane >> 4;

  {
    const u16* src = xbuf + (size_t)bid * 8192;
    #pragma unroll
    for (int c = 0; c < 4; ++c) {
      int chunk = wv * 4 + c;                       // 16 chunks x 1024B
      gload_lds16(src + chunk * 512 + lane * 8, &xt[chunk * 512]);
    }
    if (t < 128) {   // zero pad rows 128..135
      *reinterpret_cast<uint2*>(&xt[128 * 64 + t * 4]) = make_uint2(0u, 0u);
    }
  }
  asm volatile("s_waitcnt vmcnt(0)" ::: "memory");
  __syncthreads();

  f32x4 accK[8], accQ[8];
  #pragma unroll
  for (int j = 0; j < 8; ++j) { accK[j] = (f32x4)0.f; accQ[j] = (f32x4)0.f; }

  for (int kw = 0; kw < 7; ++kw) {
    #pragma unroll
    for (int ks = 0; ks < 2; ++ks) {
      const int kb = ks * 32 + g * 8;
      const size_t woff = (size_t)(kw * 64 + wv * 16 + ln) * 64 + kb;
      short8 aK = *reinterpret_cast<const short8*>(wpK + woff);
      short8 aQ = *reinterpret_cast<const short8*>(wpQ + woff);
      #pragma unroll
      for (int j = 0; j < 8; ++j) {
        int row = j * 16 + ln + kw;
        int col = kb ^ ((row & 7) << 3);
        short8 bf = *reinterpret_cast<const short8*>(&xt[row * 64 + col]);
        accK[j] = __builtin_amdgcn_mfma_f32_16x16x32_bf16(aK, bf, accK[j], 0, 0, 0);
        accQ[j] = __builtin_amdgcn_mfma_f32_16x16x32_bf16(aQ, bf, accQ[j], 0, 0, 0);
      }
    }
  }
  __syncthreads();   // xt dead -> reuse as zs

  u16* zs = xt;      // [64 co][136 n] u16 (uint4-aligned rows: 272B)
  #pragma unroll
  for (int p = 0; p < 2; ++p) {
    // transpose-in: D col = ln -> n, row = g*4+r -> co; zero n>=122
    #pragma unroll
    for (int r = 0; r < 4; ++r) {
      int co = wv * 16 + g * 4 + r;
      float bias = p ? bQ[co] : bK[co];
      #pragma unroll
      for (int j = 0; j < 8; ++j) {
        int n = j * 16 + ln;
        float v = (p ? accQ[j][r] : accK[j][r]) + bias;
        zs[co * 136 + n] = (n < 122) ? f2bf(v) : (u16)0;
      }
    }
    __syncthreads();
    // copy-out: 64 rows x 16 uint4 (256B contiguous per (co,w) row)
    const uint4* zw4 = reinterpret_cast<const uint4*>(zs);
    uint4* dst = reinterpret_cast<uint4*>(p ? qbuf : kbuf);
    #pragma unroll
    for (int pass = 0; pass < 4; ++pass) {
      int idx = t + pass * 256;        // 0..1023
      int co = idx >> 4, u = idx & 15;
      dst[((size_t)(b * 64 + co) * 256 + w) * 16 + u] = zw4[co * 17 + u];
    }
    __syncthreads();
  }
}

// ---------------------------------------------------------------
// Kernel 2a: scores via MFMA + fused masked softmax -> pbuf bf16
// q/k rows padded to 8192; pad cols are 0 in both -> dot unchanged.
// ---------------------------------------------------------------
__global__ __launch_bounds__(256) void scores_mfma(
    const u16* __restrict__ qbuf, const u16* __restrict__ kbuf,
    u16* __restrict__ pbuf)
{
  __shared__ float lmax[4][16];
  __shared__ float lsum[4][16];
  const int bid = blockIdx.x;
  const int b = bid & 15, rt = bid >> 4;
  const int t = threadIdx.x;
  const int lane = t & 63, wq = t >> 6;
  const int g = lane >> 4, ln = lane & 15;
  const int i0 = rt * 16;
  const int jbase = (rt < 8) ? 128 : 0;

  const u16* qp  = qbuf + (size_t)(b * 256 + i0 + ln) * 8192 + g * 8;
  const u16* kp0 = kbuf + (size_t)(b * 256 + jbase + wq * 32 + ln) * 8192 + g * 8;
  const u16* kp1 = kp0 + (size_t)16 * 8192;

  f32x4 acc0 = (f32x4)0.f, acc1 = (f32x4)0.f;
  #pragma unroll 4
  for (int c = 0; c < 256; ++c) {
    short8 af = *reinterpret_cast<const short8*>(qp + c * 32);
    short8 b0 = *reinterpret_cast<const short8*>(kp0 + c * 32);
    short8 b1 = *reinterpret_cast<const short8*>(kp1 + c * 32);
    acc0 = __builtin_amdgcn_mfma_f32_16x16x32_bf16(af, b0, acc0, 0, 0, 0);
    acc1 = __builtin_amdgcn_mfma_f32_16x16x32_bf16(af, b1, acc1, 0, 0, 0);
  }

  const float scale = 0.011316967f;    // 1/sqrt(7808)  (true d_k)
  float s0[4], s1[4];
  #pragma unroll
  for (int r = 0; r < 4; ++r) { s0[r] = acc0[r] * scale; s1[r] = acc1[r] * scale; }

  float pm[4], ps[4];
  #pragma unroll
  for (int r = 0; r < 4; ++r) {
    float m = fmaxf(s0[r], s1[r]);
    #pragma unroll
    for (int off = 8; off >= 1; off >>= 1) m = fmaxf(m, __shfl_xor(m, off));
    float e = __expf(s0[r] - m) + __expf(s1[r] - m);
    #pragma unroll
    for (int off = 8; off >= 1; off >>= 1) e += __shfl_xor(e, off);
    pm[r] = m; ps[r] = e;
  }
  if (ln == 0) {
    #pragma unroll
    for (int r = 0; r < 4; ++r) {
      lmax[wq][g * 4 + r] = pm[r];
      lsum[wq][g * 4 + r] = ps[r];
    }
  }
  __syncthreads();

  #pragma unroll
  for (int r = 0; r < 4; ++r) {
    int row = g * 4 + r;
    float m0 = lmax[0][row], m1 = lmax[1][row], m2 = lmax[2][row], m3 = lmax[3][row];
    float mm = fmaxf(fmaxf(m0, m1), fmaxf(m2, m3));
    float ss = lsum[0][row] * __expf(m0 - mm) + lsum[1][row] * __expf(m1 - mm)
             + lsum[2][row] * __expf(m2 - mm) + lsum[3][row] * __expf(m3 - mm);
    float inv = 1.0f / ss;
    float p0 = __expf(s0[r] - mm) * inv;
    float p1 = __expf(s1[r] - mm) * inv;
    u16* prow = pbuf + (size_t)(b * 256 + i0 + row) * 128 + wq * 32 + ln;
    prow[0]  = f2bf(p0);
    prow[16] = f2bf(p1);
  }
}

// ---------------------------------------------------------------
// Kernel 2b: z = x + P*V via MFMA -> swizzled z TILES directly (R9).
// ---------------------------------------------------------------
__global__ __launch_bounds__(256) void pv_mfma(
    const u16* __restrict__ pbuf, const float* __restrict__ x,
    u16* __restrict__ ztbuf)
{
  __shared__ u16 smem[27648];          // pl[128*136] + vt[256*40]; zs overlays
  u16* pl = smem;
  u16* vt = smem + 17408;
  const int bid = blockIdx.x;
  const int b  = bid >> 6;
  const int hb = (bid >> 5) & 1;
  const int ec = bid & 31;
  const int t = threadIdx.x;
  const int lane = t & 63, wv = t >> 6;
  const int ln = lane & 15, g = lane >> 4;

  const int i0 = hb ? 0 : 128;        // output rows
  const int jbase = hb ? 128 : 0;     // V rows (opposite half)
  const int e0 = ec * 256;
  const float* xb = x + (size_t)b * 2097152;

  // stage P (bf16 rows, pad stride 136)
  {
    const u16* pb = pbuf + (size_t)(b * 256 + i0) * 128;
    #pragma unroll
    for (int it = 0; it < 8; ++it) {
      int idx = t + it * 256;           // 0..2047 uint4
      int row = idx >> 4, c = idx & 15;
      uint4 v = *reinterpret_cast<const uint4*>(pb + row * 128 + c * 8);
      *reinterpret_cast<uint4*>(&pl[row * 136 + c * 8]) = v;
    }
  }

  f32x4 acc[2][16];
  #pragma unroll
  for (int mt = 0; mt < 2; ++mt)
    #pragma unroll
    for (int nt = 0; nt < 16; ++nt) acc[mt][nt] = (f32x4)0.f;

  uint32* vtw = reinterpret_cast<uint32*>(vt);
  for (int ks = 0; ks < 4; ++ks) {
    __syncthreads();
    // stage V^T k-step: raw V rows jbase+ks*32..+32, cols e0..e0+256
    #pragma unroll
    for (int it = 0; it < 16; ++it) {
      int idx = t + it * 256;           // 0..4095
      int e = idx & 255, jp = idx >> 8;
      const float* vr = xb + (size_t)(jbase + ks * 32 + jp * 2) * 8192 + e0 + e;
      float f0 = vr[0];
      float f1 = vr[8192];
      vtw[e * 20 + jp] = pack2(f0, f1);
    }
    __syncthreads();
    short8 af[2];
    #pragma unroll
    for (int mt = 0; mt < 2; ++mt) {
      int row = wv * 32 + mt * 16 + ln;
      af[mt] = *reinterpret_cast<const short8*>(&pl[row * 136 + ks * 32 + g * 8]);
    }
    #pragma unroll
    for (int nt = 0; nt < 16; ++nt) {
      int e = nt * 16 + ln;
      short8 bf = *reinterpret_cast<const short8*>(&vt[e * 40 + g * 8]);
      acc[0][nt] = __builtin_amdgcn_mfma_f32_16x16x32_bf16(af[0], bf, acc[0][nt], 0, 0, 0);
      acc[1][nt] = __builtin_amdgcn_mfma_f32_16x16x32_bf16(af[1], bf, acc[1][nt], 0, 0, 0);
    }
  }

  // epilogue: per-tile transpose + swizzled copy-out
  u16* zs = smem;                      // [128 h][40] u16 (stride 40 -> 16B mult)
  const int cb5 = hb ? 0 : 1;          // cbase>>5
  const int cp_base = wv * 8 + g;
  for (int r = 0; r < 4; ++r) {
    for (int dwh = 0; dwh < 2; ++dwh) {
      __syncthreads();
      #pragma unroll
      for (int mt = 0; mt < 2; ++mt) {
        int i = i0 + wv * 32 + mt * 16 + g * 4 + r;
        int cp = cp_base + mt * 4;
        const float* xr = xb + (size_t)i * 8192 + e0 + dwh * 128 + ln;
        #pragma unroll
        for (int q = 0; q < 8; ++q) {
          float z = xr[q * 16] + acc[mt][dwh * 8 + q][r];
          zs[(q * 16 + ln) * 40 + cp] = f2bf(z);
        }
      }
      __syncthreads();
      int wimg = r * 64 + ec * 2 + dwh;
      u16* tb = ztbuf + (size_t)(b * 256 + wimg) * 8192;
      #pragma unroll
      for (int pass = 0; pass < 2; ++pass) {
        int idx = t + pass * 256;      // 0..511
        int h = idx >> 2, ch = idx & 3;
        uint4 v = *reinterpret_cast<const uint4*>(&zs[h * 40 + ch * 8]);
        int blk = 32 * (cb5 ^ ((h >> 2) & 1));
        int chd = ch ^ (h & 3);
        *reinterpret_cast<uint4*>(&tb[h * 64 + blk + chd * 8]) = v;
      }
    }
  }
}

// ---------------------------------------------------------------
// Kernel 3: y = LeakyReLU(conv(z, wV) + bV) via MFMA, fp32 out (R9).
// ---------------------------------------------------------------
__global__ __launch_bounds__(256, 4) void conv_out_mfma(
    const u16* __restrict__ ztbuf, const u16* __restrict__ wpV,
    const float* __restrict__ bV, float* __restrict__ out)
{
  __shared__ uint32 smem4[8448];       // 33792B: xt (17408) then zs_f32 (33792)
  u16* xt = reinterpret_cast<u16*>(smem4);
  const int bid = blockIdx.x;
  const int b = bid >> 8, w = bid & 255;
  const int t = threadIdx.x;
  const int lane = t & 63, wv = t >> 6;
  const int ln = lane & 15, g = lane >> 4;

  {
    const u16* src = ztbuf + (size_t)bid * 8192;
    #pragma unroll
    for (int c = 0; c < 4; ++c) {
      int chunk = wv * 4 + c;
      gload_lds16(src + chunk * 512 + lane * 8, &xt[chunk * 512]);
    }
    if (t < 128) {
      *reinterpret_cast<uint2*>(&xt[128 * 64 + t * 4]) = make_uint2(0u, 0u);
    }
  }
  asm volatile("s_waitcnt vmcnt(0)" ::: "memory");
  __syncthreads();

  f32x4 acc[8];
  #pragma unroll
  for (int j = 0; j < 8; ++j) acc[j] = (f32x4)0.f;

  for (int kw = 0; kw < 7; ++kw) {
    #pragma unroll
    for (int ks = 0; ks < 2; ++ks) {
      const int kb = ks * 32 + g * 8;
      const size_t woff = (size_t)(kw * 64 + wv * 16 + ln) * 64 + kb;
      short8 aV = *reinterpret_cast<const short8*>(wpV + woff);
      #pragma unroll
      for (int j = 0; j < 8; ++j) {
        int row = j * 16 + ln + kw;
        int col = kb ^ ((row & 7) << 3);
        short8 bf = *reinterpret_cast<const short8*>(&xt[row * 64 + col]);
        acc[j] = __builtin_amdgcn_mfma_f32_16x16x32_bf16(aV, bf, acc[j], 0, 0, 0);
      }
    }
  }
  __syncthreads();   // xt dead -> zs

  float* zsf = reinterpret_cast<float*>(smem4);   // [64 co][132 n] f32
  #pragma unroll
  for (int r = 0; r < 4; ++r) {
    int co = wv * 16 + g * 4 + r;
    float bv = bV[co];
    #pragma unroll
    for (int j = 0; j < 8; ++j) {
      int n = j * 16 + ln;
      if (n < 122) {
        float y = acc[j][r] + bv;
        zsf[co * 132 + n] = (y >= 0.f) ? y : 0.2f * y;
      }
    }
  }
  __syncthreads();
  // copy-out: 64 rows x 61 uint2 (488B contiguous per (co,w) row)
  const uint2* zw = reinterpret_cast<const uint2*>(zsf);
  #pragma unroll
  for (int pass = 0; pass < 16; ++pass) {
    int idx = t + pass * 256;          // 0..4095
    int co = idx >> 6, u = idx & 63;
    if (u < 61) {
      uint2* dst = reinterpret_cast<uint2*>(
          out + ((size_t)(b * 64 + co) * 256 + w) * 122);
      dst[u] = zw[co * 66 + u];
    }
  }
}

// ---------------------------------------------------------------
extern "C" void kernel_launch(void* const* d_in, const int* in_sizes, int n_in,
                              void* d_out, int out_size, void* d_ws, size_t ws_size,
                              hipStream_t stream) {
  const float* x  = (const float*)d_in[0];
  const float* wK = (const float*)d_in[1];
  const float* bK = (const float*)d_in[2];
  const float* wQ = (const float*)d_in[3];
  const float* bQ = (const float*)d_in[4];
  const float* wV = (const float*)d_in[5];
  const float* bV = (const float*)d_in[6];
  float* out = (float*)d_out;

  // workspace layout (202,547,200 B total):
  // [0)            A: xbuf -> ztbuf  67,108,864  (xbuf dead after conv_kq;
  //                                              pv writes ztbuf here)
  // [67,108,864)   qbuf bf16 padded  67,108,864  dead after scores
  // [134,217,728)  kbuf bf16 padded  67,108,864  dead after scores
  // [201,326,592)  pbuf bf16          1,048,576  live scores->pv
  // [202,375,168)  wpK/wpQ/wpV        3x57,344   (wpV live to conv_out)
  char* ws = (char*)d_ws;
  u16* xbuf  = (u16*)ws;
  u16* ztbuf = xbuf;
  u16* qbuf  = (u16*)(ws + 67108864);
  u16* kbuf  = (u16*)(ws + 134217728);
  u16* pbuf  = (u16*)(ws + 201326592);
  u16* wpK   = (u16*)(ws + 202375168);
  u16* wpQ   = (u16*)(ws + 202432512);
  u16* wpV   = (u16*)(ws + 202489856);

  prep_weights<<<dim3(336), dim3(256), 0, stream>>>(wK, wQ, wV, wpK, wpQ, wpV);
  prep_x<<<dim3(16 * 256), dim3(256), 0, stream>>>(x, xbuf);
  conv_kq_mfma<<<dim3(16 * 256), dim3(256), 0, stream>>>(xbuf, wpK, wpQ, bK, bQ, qbuf, kbuf);
  scores_mfma<<<dim3(256), dim3(256), 0, stream>>>(qbuf, kbuf, pbuf);
  pv_mfma<<<dim3(1024), dim3(256), 0, stream>>>(pbuf, x, ztbuf);
  conv_out_mfma<<<dim3(16 * 256), dim3(256), 0, stream>>>(ztbuf, wpV, bV, out);
}

// Round 12
// 337.990 us; speedup vs baseline: 1.2344x; 1.0291x over previous
//
#include <hip/hip_runtime.h>
#include <hip/hip_bf16.h>

using uint32 = unsigned int;
using u16 = unsigned short;
using short8 = __attribute__((ext_vector_type(8))) short;
using f32x4  = __attribute__((ext_vector_type(4))) float;

// ---------- bf16 helpers ----------
__device__ __forceinline__ float bf2f(u16 u) {
  union { uint32 i; float f; } c; c.i = ((uint32)u) << 16; return c.f;
}
__device__ __forceinline__ u16 f2bf(float f) {
  union { float f; uint32 i; } c; c.f = f;
  uint32 u = c.i;
  u += 0x7fffu + ((u >> 16) & 1u);   // RNE
  return (u16)(u >> 16);
}
__device__ __forceinline__ uint32 pack2(float a, float b) {
  return (uint32)f2bf(a) | ((uint32)f2bf(b) << 16);
}

// async global->LDS, 16B per lane. LDS dest: wave-uniform base (+lane*16 by HW);
// global src: per-lane address.
__device__ __forceinline__ void gload_lds16(const void* g, void* l) {
  __builtin_amdgcn_global_load_lds(
      (const __attribute__((address_space(1))) unsigned int*)g,
      (__attribute__((address_space(3))) unsigned int*)l, 16, 0, 0);
}

// Sizes: B=16, C=64, W=256, H=128, H'=122, KW=7
// q/k stored PADDED: [b][co][w][128] bf16 (cols 122..127 = 0 in both q,k ->
// QK dot over 8192 == dot over 7808 exactly). Row map i=4co+(w>>6) unchanged.
// raw flatten: row j=(c=j>>2, wblk=j&3); col e=(dw=e>>7, h=e&127)
// x/z tiles: per (b,w) [128 h][64 ci^((h&7)<<3)] bf16, 16384B

// ---------------------------------------------------------------
// Kernel 0: prep weights -> bf16 [kw][co][ci]
// ---------------------------------------------------------------
__global__ __launch_bounds__(256) void prep_weights(
    const float* __restrict__ wK, const float* __restrict__ wQ,
    const float* __restrict__ wV,
    u16* __restrict__ pK, u16* __restrict__ pQ, u16* __restrict__ pV)
{
  int idx = blockIdx.x * 256 + threadIdx.x;   // 0..86015
  if (idx >= 86016) return;
  int set = idx / 28672;
  int r = idx - set * 28672;                  // kw*4096 + co*64 + ci
  int kw = r >> 12;
  int rem = r & 4095;
  int co = rem >> 6, ci = rem & 63;
  const float* src = set == 0 ? wK : (set == 1 ? wQ : wV);
  u16* dst = set == 0 ? pK : (set == 1 ? pQ : pV);
  dst[r] = f2bf(src[co * 448 + ci * 7 + kw]);
}

// ---------------------------------------------------------------
// Kernel 0b: x -> swizzled bf16 tiles (streaming, full occupancy)
// ---------------------------------------------------------------
__global__ __launch_bounds__(256) void prep_x(
    const float* __restrict__ x, u16* __restrict__ xbuf)
{
  __shared__ u16 xt[128 * 64];
  const int bid = blockIdx.x;         // b*256 + w
  const int b = bid >> 8, w = bid & 255;
  const int t = threadIdx.x;
  const float* xb = x + (size_t)b * 2097152 + (size_t)w * 128;
  #pragma unroll
  for (int it = 0; it < 8; ++it) {
    int idx = t + it * 256;
    int h = idx & 127, gq = idx >> 7;
    int ci0 = gq * 4;
    float v0 = xb[(size_t)(ci0 + 0) * 32768 + h];
    float v1 = xb[(size_t)(ci0 + 1) * 32768 + h];
    float v2 = xb[(size_t)(ci0 + 2) * 32768 + h];
    float v3 = xb[(size_t)(ci0 + 3) * 32768 + h];
    uint2 pk; pk.x = pack2(v0, v1); pk.y = pack2(v2, v3);
    int col = ci0 ^ ((h & 7) << 3);
    *reinterpret_cast<uint2*>(&xt[h * 64 + col]) = pk;
  }
  __syncthreads();
  const uint4* s = reinterpret_cast<const uint4*>(xt);
  uint4* d = reinterpret_cast<uint4*>(xbuf + (size_t)bid * 8192);
  #pragma unroll
  for (int it = 0; it < 4; ++it) d[t + it * 256] = s[t + it * 256];
}

// ---------------------------------------------------------------
// Kernel 1: K and Q convs via 16x16x32 MFMA (R9-proven K-loop).
// Staging = global_load_lds of pre-swizzled tile. Epilogue: LDS
// transpose -> PADDED rows (256B), fully-coalesced uint4 copy-out.
// ---------------------------------------------------------------
__global__ __launch_bounds__(256, 4) void conv_kq_mfma(
    const u16* __restrict__ xbuf,
    const u16* __restrict__ wpK, const u16* __restrict__ wpQ,
    const float* __restrict__ bK, const float* __restrict__ bQ,
    u16* __restrict__ qbuf, u16* __restrict__ kbuf)
{
  __shared__ u16 xt[136 * 64];   // staging tile; reused as zs[64 co][136 n]
  const int bid = blockIdx.x;
  const int b = bid >> 8, w = bid & 255;
  const int t = threadIdx.x;
  const int lane = t & 63, wv = t >> 6;
  const int ln = lane & 15, g = lane >> 4;

  {
    const u16* src = xbuf + (size_t)bid * 8192;
    #pragma unroll
    for (int c = 0; c < 4; ++c) {
      int chunk = wv * 4 + c;                       // 16 chunks x 1024B
      gload_lds16(src + chunk * 512 + lane * 8, &xt[chunk * 512]);
    }
    if (t < 128) {   // zero pad rows 128..135
      *reinterpret_cast<uint2*>(&xt[128 * 64 + t * 4]) = make_uint2(0u, 0u);
    }
  }
  asm volatile("s_waitcnt vmcnt(0)" ::: "memory");
  __syncthreads();

  f32x4 accK[8], accQ[8];
  #pragma unroll
  for (int j = 0; j < 8; ++j) { accK[j] = (f32x4)0.f; accQ[j] = (f32x4)0.f; }

  for (int kw = 0; kw < 7; ++kw) {
    #pragma unroll
    for (int ks = 0; ks < 2; ++ks) {
      const int kb = ks * 32 + g * 8;
      const size_t woff = (size_t)(kw * 64 + wv * 16 + ln) * 64 + kb;
      short8 aK = *reinterpret_cast<const short8*>(wpK + woff);
      short8 aQ = *reinterpret_cast<const short8*>(wpQ + woff);
      #pragma unroll
      for (int j = 0; j < 8; ++j) {
        int row = j * 16 + ln + kw;
        int col = kb ^ ((row & 7) << 3);
        short8 bf = *reinterpret_cast<const short8*>(&xt[row * 64 + col]);
        accK[j] = __builtin_amdgcn_mfma_f32_16x16x32_bf16(aK, bf, accK[j], 0, 0, 0);
        accQ[j] = __builtin_amdgcn_mfma_f32_16x16x32_bf16(aQ, bf, accQ[j], 0, 0, 0);
      }
    }
  }
  __syncthreads();   // xt dead -> reuse as zs

  u16* zs = xt;      // [64 co][136 n] u16 (uint4-aligned rows: 272B)
  #pragma unroll
  for (int p = 0; p < 2; ++p) {
    // transpose-in: D col = ln -> n, row = g*4+r -> co; zero n>=122
    #pragma unroll
    for (int r = 0; r < 4; ++r) {
      int co = wv * 16 + g * 4 + r;
      float bias = p ? bQ[co] : bK[co];
      #pragma unroll
      for (int j = 0; j < 8; ++j) {
        int n = j * 16 + ln;
        float v = (p ? accQ[j][r] : accK[j][r]) + bias;
        zs[co * 136 + n] = (n < 122) ? f2bf(v) : (u16)0;
      }
    }
    __syncthreads();
    // copy-out: 64 rows x 16 uint4 (256B contiguous per (co,w) row)
    const uint4* zw4 = reinterpret_cast<const uint4*>(zs);
    uint4* dst = reinterpret_cast<uint4*>(p ? qbuf : kbuf);
    #pragma unroll
    for (int pass = 0; pass < 4; ++pass) {
      int idx = t + pass * 256;        // 0..1023
      int co = idx >> 4, u = idx & 15;
      dst[((size_t)(b * 64 + co) * 256 + w) * 16 + u] = zw4[co * 17 + u];
    }
    __syncthreads();
  }
}

// ---------------------------------------------------------------
// Kernel 2a: scores via MFMA, SPLIT-K (16 waves), fused masked softmax.
// Block = (b, rt): 16 rows x 128 cols. wave = (kp K-part, wq col-group).
// Each wave: 16x32 partial over K=2048 (64 steps). Partials -> LDS,
// kp==0 waves sum + softmax (intra-wave shfl + cross-wave merge).
// ---------------------------------------------------------------
__global__ __launch_bounds__(1024) void scores_mfma(
    const u16* __restrict__ qbuf, const u16* __restrict__ kbuf,
    u16* __restrict__ pbuf)
{
  __shared__ float sred[4][16][128];   // 32 KB partials
  __shared__ float lmax[4][16];
  __shared__ float lsum[4][16];
  const int bid = blockIdx.x;
  const int b = bid & 15, rt = bid >> 4;
  const int t = threadIdx.x;
  const int lane = t & 63;
  const int wv = t >> 6;               // 0..15
  const int wq = wv & 3, kp = wv >> 2;
  const int g = lane >> 4, ln = lane & 15;
  const int i0 = rt * 16;
  const int jbase = (rt < 8) ? 128 : 0;

  const u16* qp  = qbuf + (size_t)(b * 256 + i0 + ln) * 8192 + kp * 2048 + g * 8;
  const u16* kp0 = kbuf + (size_t)(b * 256 + jbase + wq * 32 + ln) * 8192 + kp * 2048 + g * 8;
  const u16* kp1 = kp0 + (size_t)16 * 8192;

  f32x4 acc0 = (f32x4)0.f, acc1 = (f32x4)0.f;
  #pragma unroll 4
  for (int c = 0; c < 64; ++c) {
    short8 af = *reinterpret_cast<const short8*>(qp + c * 32);
    short8 b0 = *reinterpret_cast<const short8*>(kp0 + c * 32);
    short8 b1 = *reinterpret_cast<const short8*>(kp1 + c * 32);
    acc0 = __builtin_amdgcn_mfma_f32_16x16x32_bf16(af, b0, acc0, 0, 0, 0);
    acc1 = __builtin_amdgcn_mfma_f32_16x16x32_bf16(af, b1, acc1, 0, 0, 0);
  }

  // write partials: D col=ln, row=g*4+r
  #pragma unroll
  for (int r = 0; r < 4; ++r) {
    sred[kp][g * 4 + r][wq * 32 + ln]      = acc0[r];
    sred[kp][g * 4 + r][wq * 32 + 16 + ln] = acc1[r];
  }
  __syncthreads();

  if (kp == 0) {
    const float scale = 0.011316967f;    // 1/sqrt(7808)  (true d_k)
    float s0[4], s1[4];
    #pragma unroll
    for (int r = 0; r < 4; ++r) {
      int row = g * 4 + r;
      int c0 = wq * 32 + ln, c1 = c0 + 16;
      s0[r] = (sred[0][row][c0] + sred[1][row][c0]
             + sred[2][row][c0] + sred[3][row][c0]) * scale;
      s1[r] = (sred[0][row][c1] + sred[1][row][c1]
             + sred[2][row][c1] + sred[3][row][c1]) * scale;
    }

    float pm[4], ps[4];
    #pragma unroll
    for (int r = 0; r < 4; ++r) {
      float m = fmaxf(s0[r], s1[r]);
      #pragma unroll
      for (int off = 8; off >= 1; off >>= 1) m = fmaxf(m, __shfl_xor(m, off));
      float e = __expf(s0[r] - m) + __expf(s1[r] - m);
      #pragma unroll
      for (int off = 8; off >= 1; off >>= 1) e += __shfl_xor(e, off);
      pm[r] = m; ps[r] = e;
    }
    if (ln == 0) {
      #pragma unroll
      for (int r = 0; r < 4; ++r) {
        lmax[wq][g * 4 + r] = pm[r];
        lsum[wq][g * 4 + r] = ps[r];
      }
    }
    __builtin_amdgcn_s_barrier();      // only kp==0 waves reach here? NO ->
    // NOTE: s_barrier with divergent wave participation is unsafe; use
    // lightweight LDS handshake instead: all lmax/lsum writes are complete
    // after the 4 kp==0 waves pass this point. We re-sync via ds ordering:
    // each kp==0 wave only needs lmax/lsum of ALL wq groups.
    // (replaced below by full-block barrier pattern)
    #pragma unroll
    for (int r = 0; r < 4; ++r) {
      int row = g * 4 + r;
      float m0 = lmax[0][row], m1 = lmax[1][row], m2 = lmax[2][row], m3 = lmax[3][row];
      float mm = fmaxf(fmaxf(m0, m1), fmaxf(m2, m3));
      float ss = lsum[0][row] * __expf(m0 - mm) + lsum[1][row] * __expf(m1 - mm)
               + lsum[2][row] * __expf(m2 - mm) + lsum[3][row] * __expf(m3 - mm);
      float inv = 1.0f / ss;
      float p0 = __expf(s0[r] - mm) * inv;
      float p1 = __expf(s1[r] - mm) * inv;
      u16* prow = pbuf + (size_t)(b * 256 + i0 + row) * 128 + wq * 32 + ln;
      prow[0]  = f2bf(p0);
      prow[16] = f2bf(p1);
    }
  }
}

// ---------------------------------------------------------------
// Kernel 2b: z = x + P*V via MFMA -> swizzled z TILES directly (R9).
// ---------------------------------------------------------------
__global__ __launch_bounds__(256) void pv_mfma(
    const u16* __restrict__ pbuf, const float* __restrict__ x,
    u16* __restrict__ ztbuf)
{
  __shared__ u16 smem[27648];          // pl[128*136] + vt[256*40]; zs overlays
  u16* pl = smem;
  u16* vt = smem + 17408;
  const int bid = blockIdx.x;
  const int b  = bid >> 6;
  const int hb = (bid >> 5) & 1;
  const int ec = bid & 31;
  const int t = threadIdx.x;
  const int lane = t & 63, wv = t >> 6;
  const int ln = lane & 15, g = lane >> 4;

  const int i0 = hb ? 0 : 128;        // output rows
  const int jbase = hb ? 128 : 0;     // V rows (opposite half)
  const int e0 = ec * 256;
  const float* xb = x + (size_t)b * 2097152;

  // stage P (bf16 rows, pad stride 136)
  {
    const u16* pb = pbuf + (size_t)(b * 256 + i0) * 128;
    #pragma unroll
    for (int it = 0; it < 8; ++it) {
      int idx = t + it * 256;           // 0..2047 uint4
      int row = idx >> 4, c = idx & 15;
      uint4 v = *reinterpret_cast<const uint4*>(pb + row * 128 + c * 8);
      *reinterpret_cast<uint4*>(&pl[row * 136 + c * 8]) = v;
    }
  }

  f32x4 acc[2][16];
  #pragma unroll
  for (int mt = 0; mt < 2; ++mt)
    #pragma unroll
    for (int nt = 0; nt < 16; ++nt) acc[mt][nt] = (f32x4)0.f;

  uint32* vtw = reinterpret_cast<uint32*>(vt);
  for (int ks = 0; ks < 4; ++ks) {
    __syncthreads();
    // stage V^T k-step: raw V rows jbase+ks*32..+32, cols e0..e0+256
    #pragma unroll
    for (int it = 0; it < 16; ++it) {
      int idx = t + it * 256;           // 0..4095
      int e = idx & 255, jp = idx >> 8;
      const float* vr = xb + (size_t)(jbase + ks * 32 + jp * 2) * 8192 + e0 + e;
      float f0 = vr[0];
      float f1 = vr[8192];
      vtw[e * 20 + jp] = pack2(f0, f1);
    }
    __syncthreads();
    short8 af[2];
    #pragma unroll
    for (int mt = 0; mt < 2; ++mt) {
      int row = wv * 32 + mt * 16 + ln;
      af[mt] = *reinterpret_cast<const short8*>(&pl[row * 136 + ks * 32 + g * 8]);
    }
    #pragma unroll
    for (int nt = 0; nt < 16; ++nt) {
      int e = nt * 16 + ln;
      short8 bf = *reinterpret_cast<const short8*>(&vt[e * 40 + g * 8]);
      acc[0][nt] = __builtin_amdgcn_mfma_f32_16x16x32_bf16(af[0], bf, acc[0][nt], 0, 0, 0);
      acc[1][nt] = __builtin_amdgcn_mfma_f32_16x16x32_bf16(af[1], bf, acc[1][nt], 0, 0, 0);
    }
  }

  // epilogue: per-tile transpose + swizzled copy-out
  u16* zs = smem;                      // [128 h][40] u16 (stride 40 -> 16B mult)
  const int cb5 = hb ? 0 : 1;          // cbase>>5
  const int cp_base = wv * 8 + g;
  for (int r = 0; r < 4; ++r) {
    for (int dwh = 0; dwh < 2; ++dwh) {
      __syncthreads();
      #pragma unroll
      for (int mt = 0; mt < 2; ++mt) {
        int i = i0 + wv * 32 + mt * 16 + g * 4 + r;
        int cp = cp_base + mt * 4;
        const float* xr = xb + (size_t)i * 8192 + e0 + dwh * 128 + ln;
        #pragma unroll
        for (int q = 0; q < 8; ++q) {
          float z = xr[q * 16] + acc[mt][dwh * 8 + q][r];
          zs[(q * 16 + ln) * 40 + cp] = f2bf(z);
        }
      }
      __syncthreads();
      int wimg = r * 64 + ec * 2 + dwh;
      u16* tb = ztbuf + (size_t)(b * 256 + wimg) * 8192;
      #pragma unroll
      for (int pass = 0; pass < 2; ++pass) {
        int idx = t + pass * 256;      // 0..511
        int h = idx >> 2, ch = idx & 3;
        uint4 v = *reinterpret_cast<const uint4*>(&zs[h * 40 + ch * 8]);
        int blk = 32 * (cb5 ^ ((h >> 2) & 1));
        int chd = ch ^ (h & 3);
        *reinterpret_cast<uint4*>(&tb[h * 64 + blk + chd * 8]) = v;
      }
    }
  }
}

// ---------------------------------------------------------------
// Kernel 3: y = LeakyReLU(conv(z, wV) + bV) via MFMA, fp32 out (R9).
// ---------------------------------------------------------------
__global__ __launch_bounds__(256, 4) void conv_out_mfma(
    const u16* __restrict__ ztbuf, const u16* __restrict__ wpV,
    const float* __restrict__ bV, float* __restrict__ out)
{
  __shared__ uint32 smem4[8448];       // 33792B: xt (17408) then zs_f32 (33792)
  u16* xt = reinterpret_cast<u16*>(smem4);
  const int bid = blockIdx.x;
  const int b = bid >> 8, w = bid & 255;
  const int t = threadIdx.x;
  const int lane = t & 63, wv = t >> 6;
  const int ln = lane & 15, g = lane >> 4;

  {
    const u16* src = ztbuf + (size_t)bid * 8192;
    #pragma unroll
    for (int c = 0; c < 4; ++c) {
      int chunk = wv * 4 + c;
      gload_lds16(src + chunk * 512 + lane * 8, &xt[chunk * 512]);
    }
    if (t < 128) {
      *reinterpret_cast<uint2*>(&xt[128 * 64 + t * 4]) = make_uint2(0u, 0u);
    }
  }
  asm volatile("s_waitcnt vmcnt(0)" ::: "memory");
  __syncthreads();

  f32x4 acc[8];
  #pragma unroll
  for (int j = 0; j < 8; ++j) acc[j] = (f32x4)0.f;

  for (int kw = 0; kw < 7; ++kw) {
    #pragma unroll
    for (int ks = 0; ks < 2; ++ks) {
      const int kb = ks * 32 + g * 8;
      const size_t woff = (size_t)(kw * 64 + wv * 16 + ln) * 64 + kb;
      short8 aV = *reinterpret_cast<const short8*>(wpV + woff);
      #pragma unroll
      for (int j = 0; j < 8; ++j) {
        int row = j * 16 + ln + kw;
        int col = kb ^ ((row & 7) << 3);
        short8 bf = *reinterpret_cast<const short8*>(&xt[row * 64 + col]);
        acc[j] = __builtin_amdgcn_mfma_f32_16x16x32_bf16(aV, bf, acc[j], 0, 0, 0);
      }
    }
  }
  __syncthreads();   // xt dead -> zs

  float* zsf = reinterpret_cast<float*>(smem4);   // [64 co][132 n] f32
  #pragma unroll
  for (int r = 0; r < 4; ++r) {
    int co = wv * 16 + g * 4 + r;
    float bv = bV[co];
    #pragma unroll
    for (int j = 0; j < 8; ++j) {
      int n = j * 16 + ln;
      if (n < 122) {
        float y = acc[j][r] + bv;
        zsf[co * 132 + n] = (y >= 0.f) ? y : 0.2f * y;
      }
    }
  }
  __syncthreads();
  // copy-out: 64 rows x 61 uint2 (488B contiguous per (co,w) row)
  const uint2* zw = reinterpret_cast<const uint2*>(zsf);
  #pragma unroll
  for (int pass = 0; pass < 16; ++pass) {
    int idx = t + pass * 256;          // 0..4095
    int co = idx >> 6, u = idx & 63;
    if (u < 61) {
      uint2* dst = reinterpret_cast<uint2*>(
          out + ((size_t)(b * 64 + co) * 256 + w) * 122);
      dst[u] = zw[co * 66 + u];
    }
  }
}

// ---------------------------------------------------------------
extern "C" void kernel_launch(void* const* d_in, const int* in_sizes, int n_in,
                              void* d_out, int out_size, void* d_ws, size_t ws_size,
                              hipStream_t stream) {
  const float* x  = (const float*)d_in[0];
  const float* wK = (const float*)d_in[1];
  const float* bK = (const float*)d_in[2];
  const float* wQ = (const float*)d_in[3];
  const float* bQ = (const float*)d_in[4];
  const float* wV = (const float*)d_in[5];
  const float* bV = (const float*)d_in[6];
  float* out = (float*)d_out;

  // workspace layout (202,547,200 B total):
  // [0)            A: xbuf -> ztbuf  67,108,864  (xbuf dead after conv_kq;
  //                                              pv writes ztbuf here)
  // [67,108,864)   qbuf bf16 padded  67,108,864  dead after scores
  // [134,217,728)  kbuf bf16 padded  67,108,864  dead after scores
  // [201,326,592)  pbuf bf16          1,048,576  live scores->pv
  // [202,375,168)  wpK/wpQ/wpV        3x57,344   (wpV live to conv_out)
  char* ws = (char*)d_ws;
  u16* xbuf  = (u16*)ws;
  u16* ztbuf = xbuf;
  u16* qbuf  = (u16*)(ws + 67108864);
  u16* kbuf  = (u16*)(ws + 134217728);
  u16* pbuf  = (u16*)(ws + 201326592);
  u16* wpK   = (u16*)(ws + 202375168);
  u16* wpQ   = (u16*)(ws + 202432512);
  u16* wpV   = (u16*)(ws + 202489856);

  prep_weights<<<dim3(336), dim3(256), 0, stream>>>(wK, wQ, wV, wpK, wpQ, wpV);
  prep_x<<<dim3(16 * 256), dim3(256), 0, stream>>>(x, xbuf);
  conv_kq_mfma<<<dim3(16 * 256), dim3(256), 0, stream>>>(xbuf, wpK, wpQ, bK, bQ, qbuf, kbuf);
  scores_mfma<<<dim3(256), dim3(1024), 0, stream>>>(qbuf, kbuf, pbuf);
  pv_mfma<<<dim3(1024), dim3(256), 0, stream>>>(pbuf, x, ztbuf);
  conv_out_mfma<<<dim3(16 * 256), dim3(256), 0, stream>>>(ztbuf, wpV, bV, out);
}